// Round 9
// baseline (298.202 us; speedup 1.0000x reference)
//
#include <hip/hip_runtime.h>
#include <stdint.h>

#define N_BOX 8400
#define NCLS 80
#define PSTRIDE 85
#define NW 132            // 64-box blocks covering 8400
#define NTILE 8778        // NW*(NW+1)/2 upper-tri tiles
#define NWAVE 8
#define CONF_T 0.01f
#define NMS_T 0.2f

typedef unsigned long long u64;

// ws layout (bytes)
#define OFF_DET     0                    // 8400 x 8 f32   = 268800
#define OFF_KEYS    268800               // 8400 u64       = 67200
#define OFF_DETS    336000               // 8400 x 8 f32   = 268800
#define OFF_BOXESS  604800               // 8400 float4    = 134400
#define OFF_TILES   739200               // 8778 x 64 u64  = 4494336
#define OFF_VCNT    5233536              // 1 int

__device__ __forceinline__ unsigned fmap_desc(float f) {
    unsigned u = __float_as_uint(f);
    unsigned m = (u & 0x80000000u) ? ~u : (u | 0x80000000u); // monotone ascending
    return ~m;                                               // descending
}

__device__ __forceinline__ u64 readlane64(u64 v, int lane) {
    unsigned lo = (unsigned)__builtin_amdgcn_readlane((int)(unsigned)v, lane);
    unsigned hi = (unsigned)__builtin_amdgcn_readlane((int)(unsigned)(v >> 32), lane);
    return ((u64)hi << 32) | lo;
}

__device__ __forceinline__ u64 shfl_xor64(u64 v, int m) {
    int lo = __shfl_xor((int)(unsigned)v, m);
    int hi = __shfl_xor((int)(unsigned)(v >> 32), m);
    return ((u64)(unsigned)hi << 32) | (unsigned)lo;
}

// 64x64 bit-matrix transpose across lanes (lane = row in, lane = column out).
// Verified on-device in R8 (diagdT path, passed absmax 0).
__device__ __forceinline__ u64 bittranspose64(u64 x, int lane) {
    const u64 P0 = 0x5555555555555555ull, P1 = 0x3333333333333333ull,
              P2 = 0x0F0F0F0F0F0F0F0Full, P3 = 0x00FF00FF00FF00FFull,
              P4 = 0x0000FFFF0000FFFFull, P5 = 0x00000000FFFFFFFFull;
#define TSTEP(s, p) do {                                                 \
        u64 y = shfl_xor64(x, s);                                        \
        x = (lane & (s)) ? ((x & ~(p)) | ((y & ~(p)) >> (s)))            \
                         : ((x & (p))  | ((y & (p))  << (s)));           \
    } while (0)
    TSTEP(1, P0); TSTEP(2, P1); TSTEP(4, P2);
    TSTEP(8, P3); TSTEP(16, P4); TSTEP(32, P5);
#undef TSTEP
    return x;
}

__device__ __forceinline__ u64 wmask(int w, int V) {
    int nb = V - (w << 6);
    if (nb <= 0) return 0ull;
    if (nb >= 64) return ~0ull;
    return (1ull << nb) - 1ull;
}

// ---- kernel A: per-row preprocess, 4 lanes per row ----
__global__ __launch_bounds__(256) void prep_k(const float* __restrict__ pred,
                                              float* __restrict__ det,
                                              u64* __restrict__ keys) {
    int gt = blockIdx.x * 256 + threadIdx.x;
    int i = gt >> 2, q = gt & 3;
    if (i >= N_BOX) return;
    const float* p = pred + (size_t)i * PSTRIDE;
    int cbase = q * 20;
    float best = p[5 + cbase];
    int arg = cbase;
    for (int c = 1; c < 20; ++c) {
        float v = p[5 + cbase + c];
        if (v > best) { best = v; arg = cbase + c; }   // strict > : first max in segment
    }
    // quad-combine: larger value wins; tie -> smaller class index (numpy first-max)
    for (int d = 1; d < 4; d <<= 1) {
        float ob = __shfl_xor(best, d);
        int   oa = __shfl_xor(arg, d);
        if (ob > best || (ob == best && oa < arg)) { best = ob; arg = oa; }
    }
    if (q == 0) {
        float cx = p[0], cy = p[1], w = p[2], h = p[3], obj = p[4];
        float hw = __fmul_rn(w, 0.5f), hh = __fmul_rn(h, 0.5f);
        float x1 = __fsub_rn(cx, hw), y1 = __fsub_rn(cy, hh);
        float x2 = __fadd_rn(cx, hw), y2 = __fadd_rn(cy, hh);
        bool valid = (obj >= CONF_T);
        float score = valid ? obj : -1.0f;
        keys[i] = ((u64)fmap_desc(score) << 32) | (unsigned)i;
        float4* dr = (float4*)(det + (size_t)i * 8);
        dr[0] = make_float4(x1, y1, x2, y2);
        dr[1] = make_float4(obj, best, (float)arg, 0.0f);
    }
}

// ---- kernel B: rank + scatter. 32 keys/block, 8 j-slices, LDS reduce. ----
__global__ __launch_bounds__(256) void rank_k(const u64* __restrict__ keys,
                                              const float* __restrict__ det,
                                              float4* __restrict__ det_s,
                                              float4* __restrict__ boxes_s,
                                              int* __restrict__ vcount) {
    int t = threadIdx.x;
    int i = blockIdx.x * 32 + (t & 31);
    int s = t >> 5;                    // slice 0..7, 1050 keys each
    u64 my = (i < N_BOX) ? keys[i] : ~0ull;
    int cnt = 0, cv = 0;
    int j0 = s * 1050, j1 = j0 + 1050;
    for (int j = j0; j < j1; j += 2) {
        ulonglong2 kk = *(const ulonglong2*)(keys + j);
        cnt += (kk.x < my) + (kk.y < my);
        cv  += ((long long)kk.x >= 0) + ((long long)kk.y >= 0);
    }
    __shared__ int sc[256], sv[256];
    sc[t] = cnt; sv[t] = cv;
    __syncthreads();
    if (t < 32) {
        int r = sc[t] + sc[t + 32] + sc[t + 64] + sc[t + 96]
              + sc[t + 128] + sc[t + 160] + sc[t + 192] + sc[t + 224];
        if (i < N_BOX) {
            const float4* dr = (const float4*)(det + (size_t)i * 8);
            float4 b0 = dr[0], b1 = dr[1];
            det_s[(size_t)r * 2]     = b0;
            det_s[(size_t)r * 2 + 1] = b1;
            boxes_s[r] = b0;
        }
        if (blockIdx.x == 0 && t == 0) {
            *vcount = sv[0] + sv[32] + sv[64] + sv[96]
                    + sv[128] + sv[160] + sv[192] + sv[224];
        }
    }
}

// ---- kernel C: suppression bitmask, upper triangle, stored BIT-TRANSPOSED ----
// tiles[tri(cb)+rb][lane l] bit b = "row-box 64rb+b suppresses col-box 64cb+l".
__global__ __launch_bounds__(64) void mask_k(const float4* __restrict__ boxes_s,
                                             u64* __restrict__ tiles) {
    int tt = blockIdx.x, lane = threadIdx.x;
    // decode linear tt -> (rb, cb), rb<=cb ; f(rb) = rb*NW - rb*(rb-1)/2
    int rb = (int)((2.0f * NW + 1.0f
                    - sqrtf((2.0f * NW + 1.0f) * (2.0f * NW + 1.0f) - 8.0f * (float)tt)) * 0.5f);
    while (rb > 0 && rb * NW - rb * (rb - 1) / 2 > tt) rb--;
    while ((rb + 1) * NW - (rb + 1) * rb / 2 <= tt) rb++;
    int cb = rb + (tt - (rb * NW - rb * (rb - 1) / 2));

    __shared__ float4 cB[64];
    __shared__ float  cA[64];
    int c0 = cb * 64 + lane;
    float4 b = (c0 < N_BOX) ? boxes_s[c0] : make_float4(0.f, 0.f, 0.f, 0.f);
    cB[lane] = b;
    cA[lane] = __fmul_rn(__fsub_rn(b.z, b.x), __fsub_rn(b.w, b.y));
    __syncthreads();
    int r = rb * 64 + lane;
    bool inb = (r < N_BOX);
    float4 rx = boxes_s[inb ? r : (N_BOX - 1)];
    float ra = __fmul_rn(__fsub_rn(rx.z, rx.x), __fsub_rn(rx.w, rx.y));
    u64 bits = 0ull;
    int cbase = cb * 64;
    for (int j = 0; j < 64; ++j) {
        int c = cbase + j;
        if (c >= N_BOX || c <= r) continue;    // rows >= N_BOX yield bits==0
        float4 cx4 = cB[j];
        float ltx = fmaxf(rx.x, cx4.x), lty = fmaxf(rx.y, cx4.y);
        float rbx = fminf(rx.z, cx4.z), rby = fminf(rx.w, cx4.w);
        float wx = fmaxf(__fsub_rn(rbx, ltx), 0.0f);
        float wy = fmaxf(__fsub_rn(rby, lty), 0.0f);
        float inter = __fmul_rn(wx, wy);
        float denom = __fadd_rn(__fsub_rn(__fadd_rn(ra, cA[j]), inter), 1e-9f);
        float iou = __fdiv_rn(inter, denom);
        if (iou > NMS_T) bits |= (1ull << j);
    }
    u64 tb = bittranspose64(bits, lane);       // ALL 64 lanes participate
    tiles[((size_t)cb * (cb + 1) / 2 + rb) * 64 + lane] = tb;
}

// ---- kernel D: greedy scan via transposed tiles. ONE block, 8 waves. ----
// Per block wp (rank-order): cur bit l = OR_{w<wp} ((tiles[tri(wp)+w][l] & A_w) != 0).
// Tile loads are address-static & independent -> split across waves, pipelined.
// A_w (leader masks) kept in per-wave registers (Ra/Rb/Rc) -> 1 barrier/block
// (double-buffered LDS partials). Every wave resolves redundantly (identical).
// Masked write-out fused at the tail.
__global__ __launch_bounds__(512, 1) void scan_k(const u64* __restrict__ tiles,
                                                 const int* __restrict__ vcount,
                                                 const float* __restrict__ det_s,
                                                 float* __restrict__ out) {
    __shared__ u64 part[2][NWAVE][64];
    __shared__ u64 keepS[NW];
    int tid = threadIdx.x;
    int lane = tid & 63, wv = tid >> 6;
    int V = *vcount;
    if (tid < NW) keepS[tid] = 0ull;
    u64 Ra = 0ull, Rb = 0ull, Rc = 0ull;   // per-wave copy: A_{lane}, A_{64+lane}, A_{128+lane}
    int nblk = (V + 63) >> 6;              // <= NW

    auto getA = [&](int w) -> u64 {        // A_w; 0 for unresolved/future w
        u64 rw = (w < 64) ? Ra : (w < 128) ? Rb : Rc;
        return readlane64(rw, w & 63);
    };

    for (int wp = 0; wp < nblk; ++wp) {
        const u64* tb = tiles + ((size_t)wp * (wp + 1) / 2) * 64 + lane;
        u64 diag = tb[(size_t)wp * 64];    // issued early; consumed after barrier
        // partial column-OR over past blocks, strided by wave, 8 loads in flight.
        // Index clamped to wp (in-bounds); getA(w)==0 for w>=wp kills the garbage.
        u64 s0 = 0, s1 = 0, s2 = 0, s3 = 0;
        for (int w0 = wv; w0 < wp; w0 += 8 * NWAVE) {
            int w1 = w0 + 1 * NWAVE, w2 = w0 + 2 * NWAVE, w3 = w0 + 3 * NWAVE;
            int w4 = w0 + 4 * NWAVE, w5 = w0 + 5 * NWAVE, w6 = w0 + 6 * NWAVE, w7 = w0 + 7 * NWAVE;
            int i0 = w0, i1 = w1 < wp ? w1 : wp, i2 = w2 < wp ? w2 : wp, i3 = w3 < wp ? w3 : wp;
            int i4 = w4 < wp ? w4 : wp, i5 = w5 < wp ? w5 : wp, i6 = w6 < wp ? w6 : wp, i7 = w7 < wp ? w7 : wp;
            u64 t0 = tb[(size_t)i0 * 64], t1 = tb[(size_t)i1 * 64];
            u64 t2 = tb[(size_t)i2 * 64], t3 = tb[(size_t)i3 * 64];
            u64 t4 = tb[(size_t)i4 * 64], t5 = tb[(size_t)i5 * 64];
            u64 t6 = tb[(size_t)i6 * 64], t7 = tb[(size_t)i7 * 64];
            s0 |= t0 & getA(w0); s1 |= t1 & getA(w1);
            s2 |= t2 & getA(w2); s3 |= t3 & getA(w3);
            s0 |= t4 & getA(w4); s1 |= t5 & getA(w5);
            s2 |= t6 & getA(w6); s3 |= t7 & getA(w7);
        }
        part[wp & 1][wv][lane] = (s0 | s1) | (s2 | s3);
        __syncthreads();
        u64 s = 0;
        #pragma unroll
        for (int k = 0; k < NWAVE; ++k) s |= part[wp & 1][k][lane];
        // resolve (redundant on all waves; inputs identical)
        u64 m = wmask(wp, V);
        u64 cur = __ballot(s != 0ull);
        u64 ns = ~cur & m;
        u64 L = 0ull;
        while (ns) {
            int b = __builtin_ctzll(ns);
            L |= 1ull << b;
            u64 sup = __ballot((int)((diag >> b) & 1ull));
            ns &= ~sup;
            ns &= ~(1ull << b);
        }
        if (wp < 64)       { if (lane == wp)       Ra = L; }
        else if (wp < 128) { if (lane == wp - 64)  Rb = L; }
        else               { if (lane == wp - 128) Rc = L; }
        if (tid == 0) keepS[wp] = L;
    }
    __syncthreads();
    // fused masked write-out (7 cols)
    for (int e = tid; e < N_BOX * 7; e += 512) {
        int r = e / 7, c = e - r * 7;
        bool k = (keepS[r >> 6] >> (r & 63)) & 1ull;
        out[e] = k ? det_s[(size_t)r * 8 + c] : 0.0f;
    }
}

extern "C" void kernel_launch(void* const* d_in, const int* in_sizes, int n_in,
                              void* d_out, int out_size, void* d_ws, size_t ws_size,
                              hipStream_t stream) {
    const float* pred = (const float*)d_in[0];
    char* ws = (char*)d_ws;
    float*  det     = (float*) (ws + OFF_DET);
    u64*    keys    = (u64*)   (ws + OFF_KEYS);
    float*  det_s   = (float*) (ws + OFF_DETS);
    float4* boxes_s = (float4*)(ws + OFF_BOXESS);
    u64*    tiles   = (u64*)   (ws + OFF_TILES);
    int*    vcount  = (int*)   (ws + OFF_VCNT);

    prep_k<<<132, 256, 0, stream>>>(pred, det, keys);
    rank_k<<<264, 256, 0, stream>>>(keys, det, (float4*)det_s, boxes_s, vcount);
    mask_k<<<NTILE, 64, 0, stream>>>(boxes_s, tiles);
    scan_k<<<1, 512, 0, stream>>>(tiles, vcount, det_s, (float*)d_out);
}

// Round 10
// 156.315 us; speedup vs baseline: 1.9077x; 1.9077x over previous
//
#include <hip/hip_runtime.h>
#include <stdint.h>

#define N_BOX 8400
#define NCLS 80
#define PSTRIDE 85
#define NW 132            // 64-box blocks covering 8400
#define NTILE 8778        // NW*(NW+1)/2 upper-tri tiles
#define ZROWI N_BOX       // mask row 8400 = all zeros (dummy row target)
#define CONF_T 0.01f
#define NMS_T 0.2f

typedef unsigned long long u64;

// ws layout (bytes). diagT/sup1/sup2 ALIAS det: det is dead after rank_k;
// tiles are written by mask_k (later in-stream) — lifetimes disjoint.
#define OFF_DET     0                    // 8400 x 8 f32   = 268800
#define OFF_DIAGT   0                    // 132*64 u64     = 67584  (alias)
#define OFF_SUP1    67584                // 132*64 u64     = 67584  (alias)
#define OFF_SUP2    135168               // 132*64 u64     = 67584  (alias)
#define OFF_KEYS    268800               // 8400 u64       = 67200
#define OFF_DETS    336000               // 8400 x 8 f32   = 268800
#define OFF_BOXESS  604800               // 8400 float4    = 134400
#define OFF_MASK    739200               // 8401 x 132 u64 = 8871456 (row 8400 = zeros)
#define OFF_KEEPW   9610656              // 132 u64        = 1056
#define OFF_VCNT    9611712              // 1 int

__device__ __forceinline__ unsigned fmap_desc(float f) {
    unsigned u = __float_as_uint(f);
    unsigned m = (u & 0x80000000u) ? ~u : (u | 0x80000000u); // monotone ascending
    return ~m;                                               // descending
}

__device__ __forceinline__ u64 readlane64(u64 v, int lane) {
    unsigned lo = (unsigned)__builtin_amdgcn_readlane((int)(unsigned)v, lane);
    unsigned hi = (unsigned)__builtin_amdgcn_readlane((int)(unsigned)(v >> 32), lane);
    return ((u64)hi << 32) | lo;
}

__device__ __forceinline__ u64 shfl_xor64(u64 v, int m) {
    int lo = __shfl_xor((int)(unsigned)v, m);
    int hi = __shfl_xor((int)(unsigned)(v >> 32), m);
    return ((u64)(unsigned)hi << 32) | (unsigned)lo;
}

// 64x64 bit-matrix transpose across lanes (lane = row in, lane = column out).
// Verified on-device R8/R9 (absmax 0).
__device__ __forceinline__ u64 bittranspose64(u64 x, int lane) {
    const u64 P0 = 0x5555555555555555ull, P1 = 0x3333333333333333ull,
              P2 = 0x0F0F0F0F0F0F0F0Full, P3 = 0x00FF00FF00FF00FFull,
              P4 = 0x0000FFFF0000FFFFull, P5 = 0x00000000FFFFFFFFull;
#define TSTEP(s, p) do {                                                 \
        u64 y = shfl_xor64(x, s);                                        \
        x = (lane & (s)) ? ((x & ~(p)) | ((y & ~(p)) >> (s)))            \
                         : ((x & (p))  | ((y & (p))  << (s)));           \
    } while (0)
    TSTEP(1, P0); TSTEP(2, P1); TSTEP(4, P2);
    TSTEP(8, P3); TSTEP(16, P4); TSTEP(32, P5);
#undef TSTEP
    return x;
}

__device__ __forceinline__ u64 wmask(int w, int V) {
    int nb = V - (w << 6);
    if (nb <= 0) return 0ull;
    if (nb >= 64) return ~0ull;
    return (1ull << nb) - 1ull;
}

// ---- kernel A: per-row preprocess, 4 lanes per row; also zeroes mask row 8400 ----
__global__ __launch_bounds__(256) void prep_k(const float* __restrict__ pred,
                                              float* __restrict__ det,
                                              u64* __restrict__ keys,
                                              u64* __restrict__ mask) {
    if (blockIdx.x == 0 && threadIdx.x < NW)
        mask[(size_t)ZROWI * NW + threadIdx.x] = 0ull;     // the all-zero dummy row
    int gt = blockIdx.x * 256 + threadIdx.x;
    int i = gt >> 2, q = gt & 3;
    if (i >= N_BOX) return;
    const float* p = pred + (size_t)i * PSTRIDE;
    int cbase = q * 20;
    float best = p[5 + cbase];
    int arg = cbase;
    for (int c = 1; c < 20; ++c) {
        float v = p[5 + cbase + c];
        if (v > best) { best = v; arg = cbase + c; }   // strict > : first max in segment
    }
    // quad-combine: larger value wins; tie -> smaller class index (numpy first-max)
    for (int d = 1; d < 4; d <<= 1) {
        float ob = __shfl_xor(best, d);
        int   oa = __shfl_xor(arg, d);
        if (ob > best || (ob == best && oa < arg)) { best = ob; arg = oa; }
    }
    if (q == 0) {
        float cx = p[0], cy = p[1], w = p[2], h = p[3], obj = p[4];
        float hw = __fmul_rn(w, 0.5f), hh = __fmul_rn(h, 0.5f);
        float x1 = __fsub_rn(cx, hw), y1 = __fsub_rn(cy, hh);
        float x2 = __fadd_rn(cx, hw), y2 = __fadd_rn(cy, hh);
        bool valid = (obj >= CONF_T);
        float score = valid ? obj : -1.0f;
        keys[i] = ((u64)fmap_desc(score) << 32) | (unsigned)i;
        float4* dr = (float4*)(det + (size_t)i * 8);
        dr[0] = make_float4(x1, y1, x2, y2);
        dr[1] = make_float4(obj, best, (float)arg, 0.0f);
    }
}

// ---- kernel B: rank + scatter. 32 keys/block, 8 j-slices, LDS reduce. ----
__global__ __launch_bounds__(256) void rank_k(const u64* __restrict__ keys,
                                              const float* __restrict__ det,
                                              float4* __restrict__ det_s,
                                              float4* __restrict__ boxes_s,
                                              int* __restrict__ vcount) {
    int t = threadIdx.x;
    int i = blockIdx.x * 32 + (t & 31);
    int s = t >> 5;                    // slice 0..7, 1050 keys each
    u64 my = (i < N_BOX) ? keys[i] : ~0ull;
    int cnt = 0, cv = 0;
    int j0 = s * 1050, j1 = j0 + 1050;
    for (int j = j0; j < j1; j += 2) {
        ulonglong2 kk = *(const ulonglong2*)(keys + j);
        cnt += (kk.x < my) + (kk.y < my);
        cv  += ((long long)kk.x >= 0) + ((long long)kk.y >= 0);
    }
    __shared__ int sc[256], sv[256];
    sc[t] = cnt; sv[t] = cv;
    __syncthreads();
    if (t < 32) {
        int r = sc[t] + sc[t + 32] + sc[t + 64] + sc[t + 96]
              + sc[t + 128] + sc[t + 160] + sc[t + 192] + sc[t + 224];
        if (i < N_BOX) {
            const float4* dr = (const float4*)(det + (size_t)i * 8);
            float4 b0 = dr[0], b1 = dr[1];
            det_s[(size_t)r * 2]     = b0;
            det_s[(size_t)r * 2 + 1] = b1;
            boxes_s[r] = b0;
        }
        if (blockIdx.x == 0 && t == 0) {
            *vcount = sv[0] + sv[32] + sv[64] + sv[96]
                    + sv[128] + sv[160] + sv[192] + sv[224];
        }
    }
}

// ---- kernel C: suppression bitmask, upper triangle, row-major; tiles at
// distance d = cb-rb <= 2 are ALSO stored bit-transposed (diagT/sup1/sup2)
// so the scan can patch near-word suppression without waiting on row loads. ----
__global__ __launch_bounds__(64) void mask_k(const float4* __restrict__ boxes_s,
                                             u64* __restrict__ mask,
                                             u64* __restrict__ diagT,
                                             u64* __restrict__ sup1,
                                             u64* __restrict__ sup2) {
    int tt = blockIdx.x, lane = threadIdx.x;
    // decode linear tt -> (rb, cb), rb<=cb ; f(rb) = rb*NW - rb*(rb-1)/2
    int rb = (int)((2.0f * NW + 1.0f
                    - sqrtf((2.0f * NW + 1.0f) * (2.0f * NW + 1.0f) - 8.0f * (float)tt)) * 0.5f);
    while (rb > 0 && rb * NW - rb * (rb - 1) / 2 > tt) rb--;
    while ((rb + 1) * NW - (rb + 1) * rb / 2 <= tt) rb++;
    int cb = rb + (tt - (rb * NW - rb * (rb - 1) / 2));

    __shared__ float4 cB[64];
    __shared__ float  cA[64];
    int c0 = cb * 64 + lane;
    float4 b = (c0 < N_BOX) ? boxes_s[c0] : make_float4(0.f, 0.f, 0.f, 0.f);
    cB[lane] = b;
    cA[lane] = __fmul_rn(__fsub_rn(b.z, b.x), __fsub_rn(b.w, b.y));
    __syncthreads();
    int r = rb * 64 + lane;
    bool inb = (r < N_BOX);
    float4 rx = boxes_s[inb ? r : (N_BOX - 1)];
    float ra = __fmul_rn(__fsub_rn(rx.z, rx.x), __fsub_rn(rx.w, rx.y));
    u64 bits = 0ull;
    int cbase = cb * 64;
    for (int j = 0; j < 64; ++j) {
        int c = cbase + j;
        if (c >= N_BOX || c <= r) continue;    // rows >= N_BOX yield bits==0
        float4 cx4 = cB[j];
        float ltx = fmaxf(rx.x, cx4.x), lty = fmaxf(rx.y, cx4.y);
        float rbx = fminf(rx.z, cx4.z), rby = fminf(rx.w, cx4.w);
        float wx = fmaxf(__fsub_rn(rbx, ltx), 0.0f);
        float wy = fmaxf(__fsub_rn(rby, lty), 0.0f);
        float inter = __fmul_rn(wx, wy);
        float denom = __fadd_rn(__fsub_rn(__fadd_rn(ra, cA[j]), inter), 1e-9f);
        float iou = __fdiv_rn(inter, denom);
        if (iou > NMS_T) bits |= (1ull << j);
    }
    if (inb) mask[(size_t)r * NW + cb] = bits;
    int d = cb - rb;
    if (d <= 2) {
        u64 tb = bittranspose64(bits, lane);   // ALL 64 lanes participate
        size_t idx = (size_t)cb * 64 + lane;
        if (d == 0)      diagT[idx] = tb;
        else if (d == 1) sup1[idx]  = tb;
        else             sup2[idx]  = tb;
    }
}

// ---- kernel D: serial greedy scan, one wave, deferred row-OR pipeline ----
// Per 64-box block w:
//   cur(w) = remv[w] (lane-owned regs, contributions from blocks <= w-3)
//          | ballot(sup1T_w & A_{w-1}) | ballot(sup2T_w & A_{w-2})   [near patch]
//   resolve leaders L via diagT ballots (register-only);
//   ISSUE <=8 alive-row loads (invalid -> zero row 8400), CONSUME 3 blocks later
//   -> ~2 blocks of slack hides LLC latency; all loads unconditional & counted.
__global__ __launch_bounds__(64, 1) void scan_k(const u64* __restrict__ mask,
                                                const u64* __restrict__ diagT,
                                                const u64* __restrict__ sup1,
                                                const u64* __restrict__ sup2,
                                                const int* __restrict__ vcount,
                                                u64* __restrict__ keepw) {
    int lane = threadIdx.x;
    int V = *vcount;
    int tw = (lane < 4) ? (128 + lane) : 131;
    u64 Ra = 0ull, Rb = 0ull, Rc = 0ull;    // lane-owned remv words 2l, 2l+1, 128+l
    u64 A1 = 0ull, A2 = 0ull;               // leader masks of blocks w-1, w-2

#define DECLS(P) u64 P##A0=0,P##A1=0,P##A2=0,P##A3=0,P##A4=0,P##A5=0,P##A6=0,P##A7=0, \
                     P##B0=0,P##B1=0,P##B2=0,P##B3=0,P##B4=0,P##B5=0,P##B6=0,P##B7=0, \
                     P##C0=0,P##C1=0,P##C2=0,P##C3=0,P##C4=0,P##C5=0,P##C6=0,P##C7=0
    DECLS(s0); DECLS(s1); DECLS(s2);
#undef DECLS
    u64 td0,t10,t20, td1,t11,t21, td2,t12,t22, td3,t13,t23, td4,t14,t24, td5,t15,t25;

#define TLOAD(TD, T1, T2, wtv) do {                                      \
        int wt_ = (wtv); wt_ = wt_ < NW ? wt_ : (NW - 1);                \
        size_t ix_ = (size_t)wt_ * 64 + lane;                            \
        TD = diagT[ix_]; T1 = sup1[ix_]; T2 = sup2[ix_];                 \
    } while (0)

#define CONSUME(P) do {                                                  \
        Ra |= ((P##A0|P##A1)|(P##A2|P##A3))|((P##A4|P##A5)|(P##A6|P##A7));\
        Rb |= ((P##B0|P##B1)|(P##B2|P##B3))|((P##B4|P##B5)|(P##B6|P##B7));\
        Rc |= ((P##C0|P##C1)|(P##C2|P##C3))|((P##C4|P##C5)|(P##C6|P##C7));\
    } while (0)

#define ISSUE(P, i) do {                                                 \
        size_t ri_ = rem_ ? (size_t)(rb_ + __builtin_ctzll(rem_))        \
                          : (size_t)ZROWI;                               \
        rem_ &= rem_ - 1;                                                \
        const u64* rp_ = mask + ri_ * NW;                                \
        ulonglong2 v_ = *(const ulonglong2*)(rp_ + 2 * lane);            \
        P##A##i = v_.x; P##B##i = v_.y; P##C##i = rp_[tw];               \
    } while (0)

#define STEP(wv, P, TDu, T1u, T2u, TDl, T1l, T2l) do {                   \
        int w_ = (wv);                                                   \
        CONSUME(P);                      /* rows of block w-3 land */    \
        TLOAD(TDl, T1l, T2l, w_ + 2);    /* static prefetch */           \
        u64 rw_ = (w_ < 128) ? ((w_ & 1) ? Rb : Ra) : Rc;                \
        int sl_ = (w_ < 128) ? (w_ >> 1) : (w_ - 128);                   \
        u64 cur_ = readlane64(rw_, sl_);                                 \
        cur_ |= __ballot((T1u & A1) != 0ull);                            \
        cur_ |= __ballot((T2u & A2) != 0ull);                            \
        u64 m_ = wmask(w_, V);                                           \
        u64 ns_ = (~cur_) & m_;                                          \
        u64 L_ = 0ull;                                                   \
        while (ns_) {                    /* one iter per leader */       \
            int b_ = __builtin_ctzll(ns_);                               \
            L_ |= 1ull << b_;                                            \
            u64 sup_ = __ballot((int)((TDu >> b_) & 1ull));              \
            ns_ &= ~sup_;                                                \
            ns_ &= ~(1ull << b_);                                        \
        }                                                                \
        if (lane == 0) keepw[w_] = L_;                                   \
        A2 = A1; A1 = L_;                                                \
        u64 rem_ = L_; int rb_ = w_ << 6;                                \
        ISSUE(P, 0); ISSUE(P, 1); ISSUE(P, 2); ISSUE(P, 3);              \
        ISSUE(P, 4); ISSUE(P, 5); ISSUE(P, 6); ISSUE(P, 7);              \
        while (rem_) {                   /* >8 leaders: rare */          \
            u64 xa_ = 0, xb_ = 0, xc_ = 0;                               \
            for (int q_ = 0; q_ < 4; ++q_) {                             \
                size_t ri_ = rem_ ? (size_t)(rb_ + __builtin_ctzll(rem_))\
                                  : (size_t)ZROWI;                       \
                rem_ &= rem_ - 1;                                        \
                const u64* rp_ = mask + ri_ * NW;                        \
                ulonglong2 v_ = *(const ulonglong2*)(rp_ + 2 * lane);    \
                xa_ |= v_.x; xb_ |= v_.y; xc_ |= rp_[tw];                \
            }                                                            \
            Ra |= xa_; Rb |= xb_; Rc |= xc_;                             \
        }                                                                \
    } while (0)

    // prologue: tile sets 0,1 for blocks 0,1 (sup tiles garbage there but
    // A1=A2=0 annihilates them)
    TLOAD(td0, t10, t20, 0);
    TLOAD(td1, t11, t21, 1);

    for (int c = 0; c < NW; c += 6) {
        STEP(c + 0, s0, td0, t10, t20, td2, t12, t22);
        STEP(c + 1, s1, td1, t11, t21, td3, t13, t23);
        STEP(c + 2, s2, td2, t12, t22, td4, t14, t24);
        STEP(c + 3, s0, td3, t13, t23, td5, t15, t25);
        STEP(c + 4, s1, td4, t14, t24, td0, t10, t20);
        STEP(c + 5, s2, td5, t15, t25, td1, t11, t21);
    }
#undef STEP
#undef ISSUE
#undef CONSUME
#undef TLOAD
}

// ---- kernel E: masked write-out (7 cols) ----
__global__ __launch_bounds__(256) void out_k(const float* __restrict__ det_s,
                                             const u64* __restrict__ keepw,
                                             float* __restrict__ out) {
    int e = blockIdx.x * 256 + threadIdx.x;
    if (e >= N_BOX * 7) return;
    int r = e / 7, c = e - r * 7;
    bool k = (keepw[r >> 6] >> (r & 63)) & 1ull;
    out[e] = k ? det_s[r * 8 + c] : 0.0f;
}

extern "C" void kernel_launch(void* const* d_in, const int* in_sizes, int n_in,
                              void* d_out, int out_size, void* d_ws, size_t ws_size,
                              hipStream_t stream) {
    const float* pred = (const float*)d_in[0];
    char* ws = (char*)d_ws;
    float*  det     = (float*) (ws + OFF_DET);
    u64*    diagT   = (u64*)   (ws + OFF_DIAGT);
    u64*    sup1    = (u64*)   (ws + OFF_SUP1);
    u64*    sup2    = (u64*)   (ws + OFF_SUP2);
    u64*    keys    = (u64*)   (ws + OFF_KEYS);
    float*  det_s   = (float*) (ws + OFF_DETS);
    float4* boxes_s = (float4*)(ws + OFF_BOXESS);
    u64*    mask    = (u64*)   (ws + OFF_MASK);
    u64*    keepw   = (u64*)   (ws + OFF_KEEPW);
    int*    vcount  = (int*)   (ws + OFF_VCNT);

    prep_k<<<132, 256, 0, stream>>>(pred, det, keys, mask);
    rank_k<<<264, 256, 0, stream>>>(keys, det, (float4*)det_s, boxes_s, vcount);
    mask_k<<<NTILE, 64, 0, stream>>>(boxes_s, mask, diagT, sup1, sup2);
    scan_k<<<1, 64, 0, stream>>>(mask, diagT, sup1, sup2, vcount, keepw);
    out_k <<<(N_BOX * 7 + 255) / 256, 256, 0, stream>>>(det_s, keepw, (float*)d_out);
}

// Round 11
// 153.810 us; speedup vs baseline: 1.9388x; 1.0163x over previous
//
#include <hip/hip_runtime.h>
#include <stdint.h>

#define N_BOX 8400
#define NCLS 80
#define PSTRIDE 85
#define NW 132            // 64-box blocks covering 8400
#define NTILE 8778        // NW*(NW+1)/2 upper-tri tiles
#define ZROWI N_BOX       // mask row 8400 = all zeros (dummy row target)
#define CONF_T 0.01f
#define NMS_T 0.2f

typedef unsigned long long u64;

// ws layout (bytes). diagT/sup1/sup2/sup3 ALIAS det+keys: both are dead after
// rank_k; tiles are written by mask_k (later in-stream) — lifetimes disjoint.
#define OFF_DET     0                    // 8400 x 8 f32   = 268800
#define OFF_DIAGT   0                    // 132*64 u64     = 67584  (alias)
#define OFF_SUP1    67584                // 132*64 u64     = 67584  (alias)
#define OFF_SUP2    135168               // 132*64 u64     = 67584  (alias)
#define OFF_SUP3    202752               // 132*64 u64     = 67584  (alias, spills into keys region — keys dead too)
#define OFF_KEYS    268800               // 8400 u64       = 67200
#define OFF_DETS    336000               // 8400 x 8 f32   = 268800
#define OFF_BOXESS  604800               // 8400 float4    = 134400
#define OFF_MASK    739200               // 8401 x 132 u64 = 8871456 (row 8400 = zeros)
#define OFF_KEEPW   9610656              // 132 u64        = 1056
#define OFF_VCNT    9611712              // 1 int

__device__ __forceinline__ unsigned fmap_desc(float f) {
    unsigned u = __float_as_uint(f);
    unsigned m = (u & 0x80000000u) ? ~u : (u | 0x80000000u); // monotone ascending
    return ~m;                                               // descending
}

__device__ __forceinline__ u64 readlane64(u64 v, int lane) {
    unsigned lo = (unsigned)__builtin_amdgcn_readlane((int)(unsigned)v, lane);
    unsigned hi = (unsigned)__builtin_amdgcn_readlane((int)(unsigned)(v >> 32), lane);
    return ((u64)hi << 32) | lo;
}

__device__ __forceinline__ u64 shfl_xor64(u64 v, int m) {
    int lo = __shfl_xor((int)(unsigned)v, m);
    int hi = __shfl_xor((int)(unsigned)(v >> 32), m);
    return ((u64)(unsigned)hi << 32) | (unsigned)lo;
}

// 64x64 bit-matrix transpose across lanes (lane = row in, lane = column out).
// Verified on-device R8/R9/R10 (absmax 0).
__device__ __forceinline__ u64 bittranspose64(u64 x, int lane) {
    const u64 P0 = 0x5555555555555555ull, P1 = 0x3333333333333333ull,
              P2 = 0x0F0F0F0F0F0F0F0Full, P3 = 0x00FF00FF00FF00FFull,
              P4 = 0x0000FFFF0000FFFFull, P5 = 0x00000000FFFFFFFFull;
#define TSTEP(s, p) do {                                                 \
        u64 y = shfl_xor64(x, s);                                        \
        x = (lane & (s)) ? ((x & ~(p)) | ((y & ~(p)) >> (s)))            \
                         : ((x & (p))  | ((y & (p))  << (s)));           \
    } while (0)
    TSTEP(1, P0); TSTEP(2, P1); TSTEP(4, P2);
    TSTEP(8, P3); TSTEP(16, P4); TSTEP(32, P5);
#undef TSTEP
    return x;
}

__device__ __forceinline__ u64 wmask(int w, int V) {
    int nb = V - (w << 6);
    if (nb <= 0) return 0ull;
    if (nb >= 64) return ~0ull;
    return (1ull << nb) - 1ull;
}

// Raw barrier: LDS drained (lgkmcnt) but vmcnt pipeline PRESERVED across the
// barrier (unlike __syncthreads, which drains vmcnt(0) — the m97 stall).
// The memory clobbers also pin global loads into their issuing step.
__device__ __forceinline__ void step_barrier() {
    asm volatile("s_waitcnt lgkmcnt(0)" ::: "memory");
    __builtin_amdgcn_s_barrier();
    asm volatile("" ::: "memory");
}

// ---- kernel A: per-row preprocess, 4 lanes per row; also zeroes mask row 8400 ----
__global__ __launch_bounds__(256) void prep_k(const float* __restrict__ pred,
                                              float* __restrict__ det,
                                              u64* __restrict__ keys,
                                              u64* __restrict__ mask) {
    if (blockIdx.x == 0 && threadIdx.x < NW)
        mask[(size_t)ZROWI * NW + threadIdx.x] = 0ull;     // the all-zero dummy row
    int gt = blockIdx.x * 256 + threadIdx.x;
    int i = gt >> 2, q = gt & 3;
    if (i >= N_BOX) return;
    const float* p = pred + (size_t)i * PSTRIDE;
    int cbase = q * 20;
    float best = p[5 + cbase];
    int arg = cbase;
    for (int c = 1; c < 20; ++c) {
        float v = p[5 + cbase + c];
        if (v > best) { best = v; arg = cbase + c; }   // strict > : first max in segment
    }
    // quad-combine: larger value wins; tie -> smaller class index (numpy first-max)
    for (int d = 1; d < 4; d <<= 1) {
        float ob = __shfl_xor(best, d);
        int   oa = __shfl_xor(arg, d);
        if (ob > best || (ob == best && oa < arg)) { best = ob; arg = oa; }
    }
    if (q == 0) {
        float cx = p[0], cy = p[1], w = p[2], h = p[3], obj = p[4];
        float hw = __fmul_rn(w, 0.5f), hh = __fmul_rn(h, 0.5f);
        float x1 = __fsub_rn(cx, hw), y1 = __fsub_rn(cy, hh);
        float x2 = __fadd_rn(cx, hw), y2 = __fadd_rn(cy, hh);
        bool valid = (obj >= CONF_T);
        float score = valid ? obj : -1.0f;
        keys[i] = ((u64)fmap_desc(score) << 32) | (unsigned)i;
        float4* dr = (float4*)(det + (size_t)i * 8);
        dr[0] = make_float4(x1, y1, x2, y2);
        dr[1] = make_float4(obj, best, (float)arg, 0.0f);
    }
}

// ---- kernel B: rank + scatter. 32 keys/block, 8 j-slices, LDS reduce. ----
__global__ __launch_bounds__(256) void rank_k(const u64* __restrict__ keys,
                                              const float* __restrict__ det,
                                              float4* __restrict__ det_s,
                                              float4* __restrict__ boxes_s,
                                              int* __restrict__ vcount) {
    int t = threadIdx.x;
    int i = blockIdx.x * 32 + (t & 31);
    int s = t >> 5;                    // slice 0..7, 1050 keys each
    u64 my = (i < N_BOX) ? keys[i] : ~0ull;
    int cnt = 0, cv = 0;
    int j0 = s * 1050, j1 = j0 + 1050;
    for (int j = j0; j < j1; j += 2) {
        ulonglong2 kk = *(const ulonglong2*)(keys + j);
        cnt += (kk.x < my) + (kk.y < my);
        cv  += ((long long)kk.x >= 0) + ((long long)kk.y >= 0);
    }
    __shared__ int sc[256], sv[256];
    sc[t] = cnt; sv[t] = cv;
    __syncthreads();
    if (t < 32) {
        int r = sc[t] + sc[t + 32] + sc[t + 64] + sc[t + 96]
              + sc[t + 128] + sc[t + 160] + sc[t + 192] + sc[t + 224];
        if (i < N_BOX) {
            const float4* dr = (const float4*)(det + (size_t)i * 8);
            float4 b0 = dr[0], b1 = dr[1];
            det_s[(size_t)r * 2]     = b0;
            det_s[(size_t)r * 2 + 1] = b1;
            boxes_s[r] = b0;
        }
        if (blockIdx.x == 0 && t == 0) {
            *vcount = sv[0] + sv[32] + sv[64] + sv[96]
                    + sv[128] + sv[160] + sv[192] + sv[224];
        }
    }
}

// ---- kernel C: suppression bitmask, upper triangle, row-major; tiles at
// distance d = cb-rb <= 3 are ALSO stored bit-transposed (diagT/sup1/sup2/sup3)
// so the scan can patch near-word suppression without waiting on row loads. ----
__global__ __launch_bounds__(64) void mask_k(const float4* __restrict__ boxes_s,
                                             u64* __restrict__ mask,
                                             u64* __restrict__ diagT,
                                             u64* __restrict__ sup1,
                                             u64* __restrict__ sup2,
                                             u64* __restrict__ sup3) {
    int tt = blockIdx.x, lane = threadIdx.x;
    // decode linear tt -> (rb, cb), rb<=cb ; f(rb) = rb*NW - rb*(rb-1)/2
    int rb = (int)((2.0f * NW + 1.0f
                    - sqrtf((2.0f * NW + 1.0f) * (2.0f * NW + 1.0f) - 8.0f * (float)tt)) * 0.5f);
    while (rb > 0 && rb * NW - rb * (rb - 1) / 2 > tt) rb--;
    while ((rb + 1) * NW - (rb + 1) * rb / 2 <= tt) rb++;
    int cb = rb + (tt - (rb * NW - rb * (rb - 1) / 2));

    __shared__ float4 cB[64];
    __shared__ float  cA[64];
    int c0 = cb * 64 + lane;
    float4 b = (c0 < N_BOX) ? boxes_s[c0] : make_float4(0.f, 0.f, 0.f, 0.f);
    cB[lane] = b;
    cA[lane] = __fmul_rn(__fsub_rn(b.z, b.x), __fsub_rn(b.w, b.y));
    __syncthreads();
    int r = rb * 64 + lane;
    bool inb = (r < N_BOX);
    float4 rx = boxes_s[inb ? r : (N_BOX - 1)];
    float ra = __fmul_rn(__fsub_rn(rx.z, rx.x), __fsub_rn(rx.w, rx.y));
    u64 bits = 0ull;
    int cbase = cb * 64;
    for (int j = 0; j < 64; ++j) {
        int c = cbase + j;
        if (c >= N_BOX || c <= r) continue;    // rows >= N_BOX yield bits==0
        float4 cx4 = cB[j];
        float ltx = fmaxf(rx.x, cx4.x), lty = fmaxf(rx.y, cx4.y);
        float rbx = fminf(rx.z, cx4.z), rby = fminf(rx.w, cx4.w);
        float wx = fmaxf(__fsub_rn(rbx, ltx), 0.0f);
        float wy = fmaxf(__fsub_rn(rby, lty), 0.0f);
        float inter = __fmul_rn(wx, wy);
        float denom = __fadd_rn(__fsub_rn(__fadd_rn(ra, cA[j]), inter), 1e-9f);
        float iou = __fdiv_rn(inter, denom);
        if (iou > NMS_T) bits |= (1ull << j);
    }
    if (inb) mask[(size_t)r * NW + cb] = bits;
    int d = cb - rb;
    if (d <= 3) {
        u64 tb = bittranspose64(bits, lane);   // ALL 64 lanes participate
        size_t idx = (size_t)cb * 64 + lane;
        if (d == 0)      diagT[idx] = tb;
        else if (d == 1) sup1[idx]  = tb;
        else if (d == 2) sup2[idx]  = tb;
        else             sup3[idx]  = tb;
    }
}

// ---- kernel D: 2-wave producer/consumer greedy scan ----
// wave 0 (resolver), per block k:
//   cur = remvP[k] (LDS, rows <= k-4) | ballot(sup1_k & A1) | ballot(sup2_k & A2)
//       | ballot(sup3_k & A3); resolve leaders via diagT ballots; Lbuf[k], keepw[k].
// wave 1 (row-OR), per step j:
//   consume 8-row slot issued at step j-2 (rows of block j-3) into reg remv;
//   publish remvP[j+1] (rows <= j-3 — meets wave0's k-4 deadline);
//   read Lbuf[j-1]; issue next 8-row slot; >8 leaders drained immediately (16/batch).
// Raw s_barrier per step (lgkm drained, vmcnt pipeline preserved).
__global__ __launch_bounds__(128, 1) void scan_k(const u64* __restrict__ mask,
                                                 const u64* __restrict__ diagT,
                                                 const u64* __restrict__ sup1,
                                                 const u64* __restrict__ sup2,
                                                 const u64* __restrict__ sup3,
                                                 const int* __restrict__ vcount,
                                                 u64* __restrict__ keepw) {
    __shared__ u64 remvP[NW + 2];
    __shared__ u64 Lbuf[NW];
    int tid = threadIdx.x, lane = tid & 63, wv = tid >> 6;
    int V = *vcount;
    for (int i = tid; i < NW + 2; i += 128) remvP[i] = 0ull;
    __syncthreads();

    if (wv == 0) {
        // ---------------- wave 0: resolver ----------------
        u64 A1 = 0ull, A2 = 0ull, A3 = 0ull;
        u64 d0P, s1P, s2P, s3P, d0Q, s1Q, s2Q, s3Q;

#define TL(S, kk) do {                                                   \
        int t_ = (kk) < NW ? (kk) : (NW - 1);                            \
        size_t ix_ = (size_t)t_ * 64 + lane;                             \
        d0##S = diagT[ix_]; s1##S = sup1[ix_];                           \
        s2##S = sup2[ix_];  s3##S = sup3[ix_];                           \
    } while (0)

#define STEP0(kk, S) do {                                                \
        int k_ = (kk);                                                   \
        u64 cur_ = remvP[k_];                                            \
        cur_ |= __ballot((s1##S & A1) != 0ull);                          \
        cur_ |= __ballot((s2##S & A2) != 0ull);                          \
        cur_ |= __ballot((s3##S & A3) != 0ull);                          \
        u64 m_ = wmask(k_, V);                                           \
        u64 ns_ = (~cur_) & m_;                                          \
        u64 L_ = 0ull;                                                   \
        while (ns_) {                                                    \
            int b_ = __builtin_ctzll(ns_);                               \
            L_ |= 1ull << b_;                                            \
            u64 sup_ = __ballot((int)((d0##S >> b_) & 1ull));            \
            ns_ &= ~sup_;                                                \
            ns_ &= ~(1ull << b_);                                        \
        }                                                                \
        if (lane == 0) { Lbuf[k_] = L_; keepw[k_] = L_; }                \
        A3 = A2; A2 = A1; A1 = L_;                                       \
        TL(S, k_ + 2);                                                   \
        step_barrier();                                                  \
    } while (0)

        TL(P, 0);
        TL(Q, 1);
        for (int c = 0; c < NW; c += 2) {
            STEP0(c + 0, P);
            STEP0(c + 1, Q);
        }
#undef STEP0
#undef TL
    } else {
        // ---------------- wave 1: row-OR ----------------
        int tw = (lane < 4) ? (128 + lane) : 131;
        u64 Ra = 0ull, Rb = 0ull, Rc = 0ull;   // lane-owned remv: words 2l, 2l+1, 128+l
        u64 Pa0=0,Pa1=0,Pa2=0,Pa3=0,Pa4=0,Pa5=0,Pa6=0,Pa7=0;
        u64 Pb0=0,Pb1=0,Pb2=0,Pb3=0,Pb4=0,Pb5=0,Pb6=0,Pb7=0;
        u64 Pc0=0,Pc1=0,Pc2=0,Pc3=0,Pc4=0,Pc5=0,Pc6=0,Pc7=0;
        u64 Qa0=0,Qa1=0,Qa2=0,Qa3=0,Qa4=0,Qa5=0,Qa6=0,Qa7=0;
        u64 Qb0=0,Qb1=0,Qb2=0,Qb3=0,Qb4=0,Qb5=0,Qb6=0,Qb7=0;
        u64 Qc0=0,Qc1=0,Qc2=0,Qc3=0,Qc4=0,Qc5=0,Qc6=0,Qc7=0;

#define CONS(S) do {                                                     \
        Ra |= ((S##a0|S##a1)|(S##a2|S##a3))|((S##a4|S##a5)|(S##a6|S##a7));\
        Rb |= ((S##b0|S##b1)|(S##b2|S##b3))|((S##b4|S##b5)|(S##b6|S##b7));\
        Rc |= ((S##c0|S##c1)|(S##c2|S##c3))|((S##c4|S##c5)|(S##c6|S##c7));\
    } while (0)

#define LROW(S, i) do {                                                  \
        size_t ri_ = rem_ ? (size_t)(rbase_ + __builtin_ctzll(rem_))     \
                          : (size_t)ZROWI;                               \
        rem_ &= rem_ - 1ull;                                             \
        const u64* rp_ = mask + ri_ * NW;                                \
        ulonglong2 v_ = *(const ulonglong2*)(rp_ + 2 * lane);            \
        S##a##i = v_.x; S##b##i = v_.y; S##c##i = rp_[tw];               \
    } while (0)

#define STEP1(jj, S) do {                                                \
        int j_ = (jj);                                                   \
        CONS(S);                               /* rows of block j-3 */   \
        int w_ = j_ + 1;                                                 \
        u64 rw_ = (w_ < 128) ? ((w_ & 1) ? Rb : Ra) : Rc;                \
        int sl_ = (w_ < 128) ? (w_ >> 1) : (w_ - 128);                   \
        u64 pv_ = readlane64(rw_, sl_);                                  \
        if (lane == 0) remvP[w_] = pv_;                                  \
        u64 Lp_ = Lbuf[j_ >= 1 ? j_ - 1 : 0];                            \
        if (j_ < 1) Lp_ = 0ull;                                          \
        int rbase_ = (j_ - 1) << 6;                                      \
        u64 rem_ = Lp_;                                                  \
        LROW(S, 0); LROW(S, 1); LROW(S, 2); LROW(S, 3);                  \
        LROW(S, 4); LROW(S, 5); LROW(S, 6); LROW(S, 7);                  \
        while (rem_) {                          /* extras: 16/batch */   \
            u64 xa_ = 0, xb_ = 0, xc_ = 0;                               \
            for (int q_ = 0; q_ < 16; ++q_) {                            \
                size_t ri_ = rem_ ? (size_t)(rbase_ + __builtin_ctzll(rem_)) \
                                  : (size_t)ZROWI;                       \
                rem_ &= rem_ - 1ull;                                     \
                const u64* rp_ = mask + ri_ * NW;                        \
                ulonglong2 v_ = *(const ulonglong2*)(rp_ + 2 * lane);    \
                xa_ |= v_.x; xb_ |= v_.y; xc_ |= rp_[tw];                \
            }                                                            \
            Ra |= xa_; Rb |= xb_; Rc |= xc_;                             \
        }                                                                \
        step_barrier();                                                  \
    } while (0)

        for (int c = 0; c < NW; c += 2) {
            STEP1(c + 0, P);
            STEP1(c + 1, Q);
        }
#undef STEP1
#undef LROW
#undef CONS
    }
}

// ---- kernel E: masked write-out (7 cols) ----
__global__ __launch_bounds__(256) void out_k(const float* __restrict__ det_s,
                                             const u64* __restrict__ keepw,
                                             float* __restrict__ out) {
    int e = blockIdx.x * 256 + threadIdx.x;
    if (e >= N_BOX * 7) return;
    int r = e / 7, c = e - r * 7;
    bool k = (keepw[r >> 6] >> (r & 63)) & 1ull;
    out[e] = k ? det_s[r * 8 + c] : 0.0f;
}

extern "C" void kernel_launch(void* const* d_in, const int* in_sizes, int n_in,
                              void* d_out, int out_size, void* d_ws, size_t ws_size,
                              hipStream_t stream) {
    const float* pred = (const float*)d_in[0];
    char* ws = (char*)d_ws;
    float*  det     = (float*) (ws + OFF_DET);
    u64*    diagT   = (u64*)   (ws + OFF_DIAGT);
    u64*    sup1    = (u64*)   (ws + OFF_SUP1);
    u64*    sup2    = (u64*)   (ws + OFF_SUP2);
    u64*    sup3    = (u64*)   (ws + OFF_SUP3);
    u64*    keys    = (u64*)   (ws + OFF_KEYS);
    float*  det_s   = (float*) (ws + OFF_DETS);
    float4* boxes_s = (float4*)(ws + OFF_BOXESS);
    u64*    mask    = (u64*)   (ws + OFF_MASK);
    u64*    keepw   = (u64*)   (ws + OFF_KEEPW);
    int*    vcount  = (int*)   (ws + OFF_VCNT);

    prep_k<<<132, 256, 0, stream>>>(pred, det, keys, mask);
    rank_k<<<264, 256, 0, stream>>>(keys, det, (float4*)det_s, boxes_s, vcount);
    mask_k<<<NTILE, 64, 0, stream>>>(boxes_s, mask, diagT, sup1, sup2, sup3);
    scan_k<<<1, 128, 0, stream>>>(mask, diagT, sup1, sup2, sup3, vcount, keepw);
    out_k <<<(N_BOX * 7 + 255) / 256, 256, 0, stream>>>(det_s, keepw, (float*)d_out);
}